// Round 7
// baseline (145.937 us; speedup 1.0000x reference)
//
#include <hip/hip_runtime.h>
#include <hip/hip_bf16.h>

// Problem constants
#define B_  8
#define TQ_ 128
#define TK_ 512
#define D_  256
#define H_  256

#define KSCALE 2.8853900817779268f   // 2*log2(e): exp(2x) = exp2(KSCALE*x)

__device__ __forceinline__ float fast_exp2(float x) {
    return __builtin_amdgcn_exp2f(x);   // v_exp_f32: 2^x (trans pipe)
}

// Full-rate-VALU reciprocal: bit-trick seed + 2 Newton steps (rel err ~1e-4).
// Valid for y in [~2^-40, ~2^40]; here y = 1+e >= 1, finite.
__device__ __forceinline__ float fast_rcp(float y) {
    float r = __int_as_float(0x7EF311C3 - __float_as_int(y));
    r = r * fmaf(-y, r, 2.0f);
    r = r * fmaf(-y, r, 2.0f);
    return r;
}

__device__ __forceinline__ float wave_red_min(float v) {
#pragma unroll
    for (int o = 32; o > 0; o >>= 1) v = fminf(v, __shfl_xor(v, o));
    return v;
}
__device__ __forceinline__ float wave_red_sum(float v) {
#pragma unroll
    for (int o = 32; o > 0; o >>= 1) v += __shfl_xor(v, o);
    return v;
}

// ---------------------------------------------------------------------------
// Kernel 1: projections, outputs pre-scaled by KSCALE. 16-row tiles.
//   blocks [0,64):   qp[b][q][h]  (8 q-tiles per b)
//   blocks [64,320): kpT[b][h][k] (32 k-tiles per b, transposed out)
// 512 threads: hq = t&63 (h0=hq*4), rg = t>>6 (rows rg*2, rg*2+1).
// W loads are float4 over h (contiguous 1KB per wave per d).
// ---------------------------------------------------------------------------
__global__ __launch_bounds__(512) void proj_kernel(
    const float* __restrict__ queries, const float* __restrict__ keys,
    const float* __restrict__ Wq, const float* __restrict__ Wk,
    float* __restrict__ qp, float* __restrict__ kpT)
{
    __shared__ __align__(16) float4 xs4[16 * 64];   // 16 rows x 256 d
    __shared__ __align__(16) float tile[16 * 260];  // transpose staging (k path)

    const int t = threadIdx.x;
    const bool isQ = (blockIdx.x < 64);
    const float* X; const float* W; int b, r0;
    if (isQ) {
        b = blockIdx.x >> 3; r0 = (blockIdx.x & 7) * 16;
        X = queries + ((size_t)b * TQ_ + r0) * D_;  W = Wq;
    } else {
        int id = blockIdx.x - 64;
        b = id >> 5; r0 = (id & 31) * 16;
        X = keys + ((size_t)b * TK_ + r0) * D_;     W = Wk;
    }

    // stage 16 x 256 input tile as float4 (coalesced)
    const float4* X4 = reinterpret_cast<const float4*>(X);
    xs4[t]       = X4[t];
    xs4[t + 512] = X4[t + 512];
    __syncthreads();

    const int hq = t & 63;          // h0 = hq*4
    const int rg = t >> 6;          // 0..7
    const int rA = rg * 2, rB = rA + 1;
    const float4* W4 = reinterpret_cast<const float4*>(W) + hq;

    float4 a0 = make_float4(0.f, 0.f, 0.f, 0.f);
    float4 a1 = make_float4(0.f, 0.f, 0.f, 0.f);

#pragma unroll 4
    for (int d4 = 0; d4 < 64; ++d4) {
        const float4 xa = xs4[rA * 64 + d4];
        const float4 xb = xs4[rB * 64 + d4];
        const float4 w0 = W4[(size_t)(d4 * 4 + 0) * 64];
        const float4 w1 = W4[(size_t)(d4 * 4 + 1) * 64];
        const float4 w2 = W4[(size_t)(d4 * 4 + 2) * 64];
        const float4 w3 = W4[(size_t)(d4 * 4 + 3) * 64];
        a0.x = fmaf(w0.x, xa.x, a0.x); a0.y = fmaf(w0.y, xa.x, a0.y);
        a0.z = fmaf(w0.z, xa.x, a0.z); a0.w = fmaf(w0.w, xa.x, a0.w);
        a1.x = fmaf(w0.x, xb.x, a1.x); a1.y = fmaf(w0.y, xb.x, a1.y);
        a1.z = fmaf(w0.z, xb.x, a1.z); a1.w = fmaf(w0.w, xb.x, a1.w);
        a0.x = fmaf(w1.x, xa.y, a0.x); a0.y = fmaf(w1.y, xa.y, a0.y);
        a0.z = fmaf(w1.z, xa.y, a0.z); a0.w = fmaf(w1.w, xa.y, a0.w);
        a1.x = fmaf(w1.x, xb.y, a1.x); a1.y = fmaf(w1.y, xb.y, a1.y);
        a1.z = fmaf(w1.z, xb.y, a1.z); a1.w = fmaf(w1.w, xb.y, a1.w);
        a0.x = fmaf(w2.x, xa.z, a0.x); a0.y = fmaf(w2.y, xa.z, a0.y);
        a0.z = fmaf(w2.z, xa.z, a0.z); a0.w = fmaf(w2.w, xa.z, a0.w);
        a1.x = fmaf(w2.x, xb.z, a1.x); a1.y = fmaf(w2.y, xb.z, a1.y);
        a1.z = fmaf(w2.z, xb.z, a1.z); a1.w = fmaf(w2.w, xb.z, a1.w);
        a0.x = fmaf(w3.x, xa.w, a0.x); a0.y = fmaf(w3.y, xa.w, a0.y);
        a0.z = fmaf(w3.z, xa.w, a0.z); a0.w = fmaf(w3.w, xa.w, a0.w);
        a1.x = fmaf(w3.x, xb.w, a1.x); a1.y = fmaf(w3.y, xb.w, a1.y);
        a1.z = fmaf(w3.z, xb.w, a1.z); a1.w = fmaf(w3.w, xb.w, a1.w);
    }
    a0.x *= KSCALE; a0.y *= KSCALE; a0.z *= KSCALE; a0.w *= KSCALE;
    a1.x *= KSCALE; a1.y *= KSCALE; a1.z *= KSCALE; a1.w *= KSCALE;

    if (isQ) {
        float* dst = qp + ((size_t)b * TQ_ + r0) * H_ + hq * 4;
        *reinterpret_cast<float4*>(dst + (size_t)rA * H_) = a0;
        *reinterpret_cast<float4*>(dst + (size_t)rB * H_) = a1;
    } else {
        // transpose through LDS: tile[r][h], then write kpT[h][k] in 32B chunks
        *reinterpret_cast<float4*>(&tile[rA * 260 + hq * 4]) = a0;
        *reinterpret_cast<float4*>(&tile[rB * 260 + hq * 4]) = a1;
        __syncthreads();
        const int h = t >> 1, half = t & 1;
        float v[8];
#pragma unroll
        for (int i = 0; i < 8; ++i) v[i] = tile[(half * 8 + i) * 260 + h];
        float* dst = kpT + (size_t)b * (H_ * TK_) + (size_t)h * TK_ + r0 + half * 8;
        *reinterpret_cast<float4*>(dst)     = make_float4(v[0], v[1], v[2], v[3]);
        *reinterpret_cast<float4*>(dst + 4) = make_float4(v[4], v[5], v[6], v[7]);
    }
}

// ---------------------------------------------------------------------------
// Kernel 2: fused scores + masked softmax + PV. TWO q-rows per block.
// grid (64 q-pairs, 8 b) = 512 blocks, 512 threads -> 2 blocks/CU, 16 waves/CU.
// Score: thread t owns k=t; per h: 1 kpT load feeds 2 q. 1 trans + ~13 VALU per
// 2 elements (exp on trans pipe, reciprocal via Newton on main pipe).
// softmax(score) == softmax over k of exp2(KSCALE*(accmin - acc)).
// PV: d = t&255, half = t>>8 (split-k 2-way), 2 q accumulators.
// ---------------------------------------------------------------------------
__global__ __launch_bounds__(512) void attn_kernel(
    const float* __restrict__ qp, const float* __restrict__ kpT,
    const float* __restrict__ values, const int* __restrict__ valid_lens,
    const float* __restrict__ wv, float* __restrict__ out)
{
    __shared__ __align__(16) float2 qw[H_];    // (q0', q1') per h, pre-scaled
    __shared__ __align__(16) float wvs[H_];
    __shared__ __align__(16) float2 pe2[TK_];  // unnormalized probs (q0,q1)
    __shared__ float redm[2][8], reds[2][8];
    __shared__ float acch[2 * 256];            // PV half-1 partials

    const int t = threadIdx.x;
    const int b = blockIdx.y;
    const int q0 = blockIdx.x * 2;

    const int len = valid_lens[b];

    // stage q-pair + wv
    const float* qpb = qp + ((size_t)b * TQ_ + q0) * H_;
    if (t < 256) qw[t] = make_float2(qpb[t], qpb[256 + t]);
    else         wvs[t - 256] = wv[t - 256];
    __syncthreads();

    // ---- score loop: k = t, all 256 h, 2 q per kk load ----
    const int k = t;
    const float* kcol = kpT + (size_t)b * (H_ * TK_) + k;
    float a0 = 0.f, a1 = 0.f;
#pragma unroll 8
    for (int h = 0; h < H_; ++h) {
        const float kk = kcol[(size_t)h * TK_];
        const float2 q2 = qw[h];
        const float w = wvs[h];
        const float e0 = fast_exp2(q2.x + kk);
        const float e1 = fast_exp2(q2.y + kk);
        a0 = fmaf(w, fast_rcp(1.0f + e0), a0);
        a1 = fmaf(w, fast_rcp(1.0f + e1), a1);
    }

    // ---- masked softmax over k (min of acc == max of score) ----
    const int lane = t & 63, wid = t >> 6;
    const bool valid = (k < len);
    const float BIG = 3.0e38f;

    float m0 = wave_red_min(valid ? a0 : BIG);
    float m1 = wave_red_min(valid ? a1 : BIG);
    if (lane == 0) { redm[0][wid] = m0; redm[1][wid] = m1; }
    __syncthreads();
    float mr0 = redm[0][0], mr1 = redm[1][0];
#pragma unroll
    for (int i = 1; i < 8; ++i) { mr0 = fminf(mr0, redm[0][i]); mr1 = fminf(mr1, redm[1][i]); }

    const float e0 = valid ? fast_exp2((mr0 - a0) * KSCALE) : 0.f;
    const float e1 = valid ? fast_exp2((mr1 - a1) * KSCALE) : 0.f;
    pe2[k] = make_float2(e0, e1);
    float S0 = wave_red_sum(e0);
    float S1 = wave_red_sum(e1);
    if (lane == 0) { reds[0][wid] = S0; reds[1][wid] = S1; }
    __syncthreads();
    float s0 = 0.f, s1 = 0.f;
#pragma unroll
    for (int i = 0; i < 8; ++i) { s0 += reds[0][i]; s1 += reds[1][i]; }
    const float rs0 = 1.0f / s0, rs1 = 1.0f / s1;

    // ---- PV: 2-way split-k ----
    const int d = t & 255;
    const int half = t >> 8;
    float c0 = 0.f, c1 = 0.f;
    const float* vb = values + (size_t)b * (TK_ * D_) + (size_t)(half * 256) * D_ + d;
    const float2* pb = &pe2[half * 256];
#pragma unroll 8
    for (int kk = 0; kk < 256; ++kk) {
        const float v = vb[(size_t)kk * D_];
        const float2 p = pb[kk];
        c0 = fmaf(p.x, v, c0);
        c1 = fmaf(p.y, v, c1);
    }
    if (half == 1) { acch[d] = c0; acch[256 + d] = c1; }
    __syncthreads();
    if (half == 0) {
        float* ob = out + ((size_t)b * TQ_ + q0) * D_ + d;
        ob[0]  = (c0 + acch[d])       * rs0;
        ob[D_] = (c1 + acch[256 + d]) * rs1;
    }
}

extern "C" void kernel_launch(void* const* d_in, const int* in_sizes, int n_in,
                              void* d_out, int out_size, void* d_ws, size_t ws_size,
                              hipStream_t stream) {
    const float* queries    = (const float*)d_in[0];
    const float* keys       = (const float*)d_in[1];
    const float* values     = (const float*)d_in[2];
    const int*   valid_lens = (const int*)  d_in[3];
    const float* Wq         = (const float*)d_in[4];
    const float* Wk         = (const float*)d_in[5];
    const float* wv         = (const float*)d_in[6];
    float* out = (float*)d_out;

    float* qp  = (float*)d_ws;                       // B*Tq*H  = 262144 f32
    float* kpT = qp + (size_t)B_ * TQ_ * H_;         // B*H*Tk  = 1048576 f32

    proj_kernel<<<320, 512, 0, stream>>>(queries, keys, Wq, Wk, qp, kpT);
    attn_kernel<<<dim3(TQ_ / 2, B_), 512, 0, stream>>>(qp, kpT, values, valid_lens, wv, out);
}

// Round 9
// 139.870 us; speedup vs baseline: 1.0434x; 1.0434x over previous
//
#include <hip/hip_runtime.h>
#include <hip/hip_bf16.h>

// Problem constants
#define B_  8
#define TQ_ 128
#define TK_ 512
#define D_  256
#define H_  256

#define KSCALE 2.8853900817779268f   // 2*log2(e): exp(2x) = exp2(KSCALE*x)

__device__ __forceinline__ float fast_exp2(float x) {
    return __builtin_amdgcn_exp2f(x);   // v_exp_f32: 2^x
}
__device__ __forceinline__ float fast_rcp(float y) {
    return __builtin_amdgcn_rcpf(y);
}

__device__ __forceinline__ float wave_red_min(float v) {
#pragma unroll
    for (int o = 32; o > 0; o >>= 1) v = fminf(v, __shfl_xor(v, o));
    return v;
}
__device__ __forceinline__ float wave_red_sum(float v) {
#pragma unroll
    for (int o = 32; o > 0; o >>= 1) v += __shfl_xor(v, o);
    return v;
}

// ---------------------------------------------------------------------------
// Kernel 1: projections, outputs pre-scaled by KSCALE. 16-row tiles.
//   blocks [0,64):   qp[b][q][h] = KSCALE * queries·Wq      (8 q-tiles per b)
//   blocks [64,320): kp[b][k][h] = KSCALE * keys·Wk         (32 k-tiles per b)
// kp is ROW-major over h now (no transpose). k-tiles with r0 >= len skipped.
// 512 threads: hq = t&63 (h0=hq*4), rg = t>>6 (rows 2rg, 2rg+1).
// ---------------------------------------------------------------------------
__global__ __launch_bounds__(512) void proj_kernel(
    const float* __restrict__ queries, const float* __restrict__ keys,
    const float* __restrict__ Wq, const float* __restrict__ Wk,
    const int* __restrict__ valid_lens,
    float* __restrict__ qp, float* __restrict__ kp)
{
    __shared__ __align__(16) float4 xs4[16 * 64];   // 16 rows x 256 d

    const int t = threadIdx.x;
    const bool isQ = (blockIdx.x < 64);
    const float* X; const float* W; float* dst; int b, r0;
    if (isQ) {
        b = blockIdx.x >> 3; r0 = (blockIdx.x & 7) * 16;
        X = queries + ((size_t)b * TQ_ + r0) * D_;  W = Wq;
        dst = qp + ((size_t)b * TQ_ + r0) * H_;
    } else {
        int id = blockIdx.x - 64;
        b = id >> 5; r0 = (id & 31) * 16;
        if (r0 >= valid_lens[b]) return;   // masked keys never read downstream
        X = keys + ((size_t)b * TK_ + r0) * D_;     W = Wk;
        dst = kp + ((size_t)b * TK_ + r0) * H_;
    }

    // stage 16 x 256 input tile as float4 (coalesced)
    const float4* X4 = reinterpret_cast<const float4*>(X);
    xs4[t]       = X4[t];
    xs4[t + 512] = X4[t + 512];
    __syncthreads();

    const int hq = t & 63;          // h0 = hq*4
    const int rg = t >> 6;          // 0..7
    const int rA = rg * 2, rB = rA + 1;
    const float4* W4 = reinterpret_cast<const float4*>(W) + hq;

    float4 a0 = make_float4(0.f, 0.f, 0.f, 0.f);
    float4 a1 = make_float4(0.f, 0.f, 0.f, 0.f);

#pragma unroll 4
    for (int d4 = 0; d4 < 64; ++d4) {
        const float4 xa = xs4[rA * 64 + d4];
        const float4 xb = xs4[rB * 64 + d4];
        const float4 w0 = W4[(size_t)(d4 * 4 + 0) * 64];
        const float4 w1 = W4[(size_t)(d4 * 4 + 1) * 64];
        const float4 w2 = W4[(size_t)(d4 * 4 + 2) * 64];
        const float4 w3 = W4[(size_t)(d4 * 4 + 3) * 64];
        a0.x = fmaf(w0.x, xa.x, a0.x); a0.y = fmaf(w0.y, xa.x, a0.y);
        a0.z = fmaf(w0.z, xa.x, a0.z); a0.w = fmaf(w0.w, xa.x, a0.w);
        a1.x = fmaf(w0.x, xb.x, a1.x); a1.y = fmaf(w0.y, xb.x, a1.y);
        a1.z = fmaf(w0.z, xb.x, a1.z); a1.w = fmaf(w0.w, xb.x, a1.w);
        a0.x = fmaf(w1.x, xa.y, a0.x); a0.y = fmaf(w1.y, xa.y, a0.y);
        a0.z = fmaf(w1.z, xa.y, a0.z); a0.w = fmaf(w1.w, xa.y, a0.w);
        a1.x = fmaf(w1.x, xb.y, a1.x); a1.y = fmaf(w1.y, xb.y, a1.y);
        a1.z = fmaf(w1.z, xb.y, a1.z); a1.w = fmaf(w1.w, xb.y, a1.w);
        a0.x = fmaf(w2.x, xa.z, a0.x); a0.y = fmaf(w2.y, xa.z, a0.y);
        a0.z = fmaf(w2.z, xa.z, a0.z); a0.w = fmaf(w2.w, xa.z, a0.w);
        a1.x = fmaf(w2.x, xb.z, a1.x); a1.y = fmaf(w2.y, xb.z, a1.y);
        a1.z = fmaf(w2.z, xb.z, a1.z); a1.w = fmaf(w2.w, xb.z, a1.w);
        a0.x = fmaf(w3.x, xa.w, a0.x); a0.y = fmaf(w3.y, xa.w, a0.y);
        a0.z = fmaf(w3.z, xa.w, a0.z); a0.w = fmaf(w3.w, xa.w, a0.w);
        a1.x = fmaf(w3.x, xb.w, a1.x); a1.y = fmaf(w3.y, xb.w, a1.y);
        a1.z = fmaf(w3.z, xb.w, a1.z); a1.w = fmaf(w3.w, xb.w, a1.w);
    }
    a0.x *= KSCALE; a0.y *= KSCALE; a0.z *= KSCALE; a0.w *= KSCALE;
    a1.x *= KSCALE; a1.y *= KSCALE; a1.z *= KSCALE; a1.w *= KSCALE;

    *reinterpret_cast<float4*>(dst + (size_t)rA * H_ + hq * 4) = a0;
    *reinterpret_cast<float4*>(dst + (size_t)rB * H_ + hq * 4) = a1;
}

// ---------------------------------------------------------------------------
// Kernel 2: fused scores + masked softmax + PV. TWO q-rows per block.
// grid (64 q-pairs, 8 b) = 512 blocks, 512 threads -> 2 blocks/CU.
// Score: thread t owns k=t, streams its own kp row [k][h] with float4 loads.
// Waves whose whole k-range is masked (64*wid >= len) skip the h-loop.
// softmax(score) == softmax over k of exp2(KSCALE*(accmin - acc)).
// PV: d = t&255, half = t>>8 (split-k 2-way); dead 64-k chunks skipped.
// ---------------------------------------------------------------------------
__global__ __launch_bounds__(512) void attn_kernel(
    const float* __restrict__ qp, const float* __restrict__ kp,
    const float* __restrict__ values, const int* __restrict__ valid_lens,
    const float* __restrict__ wv, float* __restrict__ out)
{
    __shared__ __align__(16) float qw0[H_], qw1[H_], wvs[H_];
    __shared__ __align__(16) float2 pe2[TK_];   // unnormalized probs (q0,q1)
    __shared__ float redm[2][8], reds[2][8];
    __shared__ float acch[2][256];              // PV half-1 partials

    const int t = threadIdx.x;
    const int b = blockIdx.y;
    const int q0 = blockIdx.x * 2;
    const int len = valid_lens[b];

    // stage q-pair rows + wv
    const float* qpb = qp + ((size_t)b * TQ_ + q0) * H_;
    if (t < 256) { qw0[t] = qpb[t]; qw1[t] = qpb[H_ + t]; }
    else         wvs[t - 256] = wv[t - 256];
    __syncthreads();

    // ---- score loop: k = t, float4 over h; skip fully-masked waves ----
    const int k = t, lane = t & 63, wid = t >> 6;
    float a0 = 0.f, a1 = 0.f;
    if (wid * 64 < len) {
        const float4* kr  = reinterpret_cast<const float4*>(kp + ((size_t)b * TK_ + k) * H_);
        const float4* q04 = reinterpret_cast<const float4*>(qw0);
        const float4* q14 = reinterpret_cast<const float4*>(qw1);
        const float4* wv4 = reinterpret_cast<const float4*>(wvs);
#pragma unroll 4
        for (int h4 = 0; h4 < 64; ++h4) {
            const float4 kk = kr[h4];
            const float4 qa = q04[h4];
            const float4 qb = q14[h4];
            const float4 w  = wv4[h4];
            a0 = fmaf(w.x, fast_rcp(1.0f + fast_exp2(qa.x + kk.x)), a0);
            a1 = fmaf(w.x, fast_rcp(1.0f + fast_exp2(qb.x + kk.x)), a1);
            a0 = fmaf(w.y, fast_rcp(1.0f + fast_exp2(qa.y + kk.y)), a0);
            a1 = fmaf(w.y, fast_rcp(1.0f + fast_exp2(qb.y + kk.y)), a1);
            a0 = fmaf(w.z, fast_rcp(1.0f + fast_exp2(qa.z + kk.z)), a0);
            a1 = fmaf(w.z, fast_rcp(1.0f + fast_exp2(qb.z + kk.z)), a1);
            a0 = fmaf(w.w, fast_rcp(1.0f + fast_exp2(qa.w + kk.w)), a0);
            a1 = fmaf(w.w, fast_rcp(1.0f + fast_exp2(qb.w + kk.w)), a1);
        }
    }

    // ---- masked softmax over k (min of acc == max of score) ----
    const bool valid = (k < len);
    const float BIG = 3.0e38f;

    float m0 = wave_red_min(valid ? a0 : BIG);
    float m1 = wave_red_min(valid ? a1 : BIG);
    if (lane == 0) { redm[0][wid] = m0; redm[1][wid] = m1; }
    __syncthreads();
    float mr0 = redm[0][0], mr1 = redm[1][0];
#pragma unroll
    for (int i = 1; i < 8; ++i) { mr0 = fminf(mr0, redm[0][i]); mr1 = fminf(mr1, redm[1][i]); }

    const float e0 = valid ? fast_exp2((mr0 - a0) * KSCALE) : 0.f;
    const float e1 = valid ? fast_exp2((mr1 - a1) * KSCALE) : 0.f;
    pe2[k] = make_float2(e0, e1);
    float S0 = wave_red_sum(e0);
    float S1 = wave_red_sum(e1);
    if (lane == 0) { reds[0][wid] = S0; reds[1][wid] = S1; }
    __syncthreads();
    float s0 = 0.f, s1 = 0.f;
#pragma unroll
    for (int i = 0; i < 8; ++i) { s0 += reds[0][i]; s1 += reds[1][i]; }
    const float rs0 = 1.0f / s0, rs1 = 1.0f / s1;

    // ---- PV: 2-way split-k, dead 64-k chunks skipped ----
    const int d = t & 255;
    const int half = t >> 8;
    float c0 = 0.f, c1 = 0.f;
    const float* vb = values + (size_t)b * (TK_ * D_) + (size_t)(half * 256) * D_ + d;
    const float2* pb = &pe2[half * 256];
#pragma unroll
    for (int c = 0; c < 4; ++c) {
        if (half * 256 + c * 64 < len) {
#pragma unroll 8
            for (int i = 0; i < 64; ++i) {
                const int kk = c * 64 + i;
                const float v = vb[(size_t)kk * D_];
                const float2 p = pb[kk];
                c0 = fmaf(p.x, v, c0);
                c1 = fmaf(p.y, v, c1);
            }
        }
    }
    if (half == 1) { acch[0][d] = c0; acch[1][d] = c1; }
    __syncthreads();
    if (half == 0) {
        float* ob = out + ((size_t)b * TQ_ + q0) * D_ + d;
        ob[0]  = (c0 + acch[0][d]) * rs0;
        ob[D_] = (c1 + acch[1][d]) * rs1;
    }
}

extern "C" void kernel_launch(void* const* d_in, const int* in_sizes, int n_in,
                              void* d_out, int out_size, void* d_ws, size_t ws_size,
                              hipStream_t stream) {
    const float* queries    = (const float*)d_in[0];
    const float* keys       = (const float*)d_in[1];
    const float* values     = (const float*)d_in[2];
    const int*   valid_lens = (const int*)  d_in[3];
    const float* Wq         = (const float*)d_in[4];
    const float* Wk         = (const float*)d_in[5];
    const float* wv         = (const float*)d_in[6];
    float* out = (float*)d_out;

    float* qp = (float*)d_ws;                        // B*Tq*H  = 262144 f32
    float* kp = qp + (size_t)B_ * TQ_ * H_;          // B*Tk*H  = 1048576 f32

    proj_kernel<<<320, 512, 0, stream>>>(queries, keys, Wq, Wk, valid_lens, qp, kp);
    attn_kernel<<<dim3(TQ_ / 2, B_), 512, 0, stream>>>(qp, kp, values, valid_lens, wv, out);
}

// Round 13
// 121.281 us; speedup vs baseline: 1.2033x; 1.1533x over previous
//
#include <hip/hip_runtime.h>
#include <hip/hip_bf16.h>

// Problem constants
#define B_  8
#define TQ_ 128
#define TK_ 512
#define D_  256
#define H_  256

#define KSCALE 2.8853900817779268f   // 2*log2(e): exp(2x) = exp2(KSCALE*x)

__device__ __forceinline__ float fast_exp2(float x) {
    return __builtin_amdgcn_exp2f(x);   // v_exp_f32: 2^x
}
__device__ __forceinline__ float fast_rcp(float y) {
    return __builtin_amdgcn_rcpf(y);
}

__device__ __forceinline__ float wave_red_min(float v) {
#pragma unroll
    for (int o = 32; o > 0; o >>= 1) v = fminf(v, __shfl_xor(v, o));
    return v;
}
__device__ __forceinline__ float wave_red_sum(float v) {
#pragma unroll
    for (int o = 32; o > 0; o >>= 1) v += __shfl_xor(v, o);
    return v;
}

// ---------------------------------------------------------------------------
// Kernel 1: projections (d-split), outputs pre-scaled by KSCALE. 16-row tiles.
//   blocks [0,64):   qp[b][q][h] = KSCALE * queries·Wq   (8 q-tiles per b)
//   blocks [64,320): kp[b][k][h] = KSCALE * keys·Wk      (32 k-tiles per b, skip if masked)
// 512 threads = 64 hq (4 h each) x 4 ds (64 d each) x 2 rg (8 rows each).
// Each W element read at most 2x per block (vs 8x before); 1-deep W prefetch.
// LDS reduction over the 4 d-slices at the end.
// ---------------------------------------------------------------------------
__global__ __launch_bounds__(512) void proj_kernel(
    const float* __restrict__ queries, const float* __restrict__ keys,
    const float* __restrict__ Wq, const float* __restrict__ Wk,
    const int* __restrict__ valid_lens,
    float* __restrict__ qp, float* __restrict__ kp)
{
    __shared__ __align__(16) float4 xs4[16 * 64];       // 16 rows x 256 d (16KB)
    __shared__ __align__(16) float4 red[2][4][8][64];   // [rg][ds][r][hq] (64KB)

    const int t = threadIdx.x;
    const bool isQ = (blockIdx.x < 64);
    const float* X; const float* W; float* dst; int b, r0;
    if (isQ) {
        b = blockIdx.x >> 3; r0 = (blockIdx.x & 7) * 16;
        X = queries + ((size_t)b * TQ_ + r0) * D_;  W = Wq;
        dst = qp + ((size_t)b * TQ_ + r0) * H_;
    } else {
        int id = blockIdx.x - 64;
        b = id >> 5; r0 = (id & 31) * 16;
        if (r0 >= valid_lens[b]) return;   // masked keys never read downstream
        X = keys + ((size_t)b * TK_ + r0) * D_;     W = Wk;
        dst = kp + ((size_t)b * TK_ + r0) * H_;
    }

    // stage 16 x 256 input tile as float4 (coalesced)
    const float4* X4 = reinterpret_cast<const float4*>(X);
    xs4[t]       = X4[t];
    xs4[t + 512] = X4[t + 512];
    __syncthreads();

    const int hq = t & 63;            // h0 = hq*4
    const int ds = (t >> 6) & 3;      // d-slice: 64 d each
    const int rg = t >> 8;            // 0/1: rows 0-7 / 8-15
    const int rbase = rg * 8;
    const float4* W4 = reinterpret_cast<const float4*>(W) + hq;

    float4 acc[8];
#pragma unroll
    for (int r = 0; r < 8; ++r) acc[r] = make_float4(0.f, 0.f, 0.f, 0.f);

    // 1-deep prefetched W rows (4 per f4-d step)
    const int d4base = ds * 16;
    float4 w0 = W4[(size_t)(4 * d4base + 0) * 64];
    float4 w1 = W4[(size_t)(4 * d4base + 1) * 64];
    float4 w2 = W4[(size_t)(4 * d4base + 2) * 64];
    float4 w3 = W4[(size_t)(4 * d4base + 3) * 64];

    for (int i = 0; i < 16; ++i) {
        const int d4 = d4base + i;
        const int d4n = d4base + ((i + 1) & 15);   // wraps harmlessly on last iter
        const float4 n0 = W4[(size_t)(4 * d4n + 0) * 64];
        const float4 n1 = W4[(size_t)(4 * d4n + 1) * 64];
        const float4 n2 = W4[(size_t)(4 * d4n + 2) * 64];
        const float4 n3 = W4[(size_t)(4 * d4n + 3) * 64];
#pragma unroll
        for (int r = 0; r < 8; ++r) {
            const float4 x = xs4[(rbase + r) * 64 + d4];
            acc[r].x = fmaf(x.x, w0.x, acc[r].x); acc[r].y = fmaf(x.x, w0.y, acc[r].y);
            acc[r].z = fmaf(x.x, w0.z, acc[r].z); acc[r].w = fmaf(x.x, w0.w, acc[r].w);
            acc[r].x = fmaf(x.y, w1.x, acc[r].x); acc[r].y = fmaf(x.y, w1.y, acc[r].y);
            acc[r].z = fmaf(x.y, w1.z, acc[r].z); acc[r].w = fmaf(x.y, w1.w, acc[r].w);
            acc[r].x = fmaf(x.z, w2.x, acc[r].x); acc[r].y = fmaf(x.z, w2.y, acc[r].y);
            acc[r].z = fmaf(x.z, w2.z, acc[r].z); acc[r].w = fmaf(x.z, w2.w, acc[r].w);
            acc[r].x = fmaf(x.w, w3.x, acc[r].x); acc[r].y = fmaf(x.w, w3.y, acc[r].y);
            acc[r].z = fmaf(x.w, w3.z, acc[r].z); acc[r].w = fmaf(x.w, w3.w, acc[r].w);
        }
        w0 = n0; w1 = n1; w2 = n2; w3 = n3;
    }

    // reduce over the 4 d-slices through LDS
#pragma unroll
    for (int r = 0; r < 8; ++r) red[rg][ds][r][hq] = acc[r];
    __syncthreads();

#pragma unroll
    for (int o = 0; o < 2; ++o) {
        const int oid = t + o * 512;          // 1024 outputs (16 r x 64 hq)
        const int r   = oid >> 6;
        const int hqo = oid & 63;
        const float4 s0 = red[r >> 3][0][r & 7][hqo];
        const float4 s1 = red[r >> 3][1][r & 7][hqo];
        const float4 s2 = red[r >> 3][2][r & 7][hqo];
        const float4 s3 = red[r >> 3][3][r & 7][hqo];
        float4 s;
        s.x = ((s0.x + s1.x) + (s2.x + s3.x)) * KSCALE;
        s.y = ((s0.y + s1.y) + (s2.y + s3.y)) * KSCALE;
        s.z = ((s0.z + s1.z) + (s2.z + s3.z)) * KSCALE;
        s.w = ((s0.w + s1.w) + (s2.w + s3.w)) * KSCALE;
        *reinterpret_cast<float4*>(dst + (size_t)r * H_ + hqo * 4) = s;
    }
}

// ---------------------------------------------------------------------------
// Kernel 2: fused scores + masked softmax + PV. TWO q-rows per block.
// grid (8 b, 64 q-pairs): b varies FASTEST across block ids -> each CU gets a
// mix of batches, equalizing the len-dependent work (load balance).
// Score: thread t owns k=t, streams its own kp row [k][h] with 2-deep float4
// prefetch. Waves whose whole k-range is masked skip the h-loop.
// softmax(score) == softmax over k of exp2(KSCALE*(accmin - acc)).
// PV: d = t&255, half = t>>8 (split-k 2-way); dead 64-k chunks skipped.
// ---------------------------------------------------------------------------
__global__ __launch_bounds__(512) void attn_kernel(
    const float* __restrict__ qp, const float* __restrict__ kp,
    const float* __restrict__ values, const int* __restrict__ valid_lens,
    const float* __restrict__ wv, float* __restrict__ out)
{
    __shared__ __align__(16) float qw0[H_], qw1[H_], wvs[H_];
    __shared__ __align__(16) float2 pe2[TK_];   // unnormalized probs (q0,q1)
    __shared__ float redm[2][8], reds[2][8];
    __shared__ float acch[2][256];              // PV half-1 partials

    const int t = threadIdx.x;
    const int b = blockIdx.x;                   // fastest-varying: balance
    const int q0 = blockIdx.y * 2;
    const int len = valid_lens[b];

    // stage q-pair rows + wv
    const float* qpb = qp + ((size_t)b * TQ_ + q0) * H_;
    if (t < 256) { qw0[t] = qpb[t]; qw1[t] = qpb[H_ + t]; }
    else         wvs[t - 256] = wv[t - 256];
    __syncthreads();

    // ---- score loop: k = t, 2-deep float4 prefetch over h ----
    const int k = t, lane = t & 63, wid = t >> 6;
    float a0 = 0.f, a1 = 0.f;
    if (wid * 64 < len) {
        const float4* kr  = reinterpret_cast<const float4*>(kp + ((size_t)b * TK_ + k) * H_);
        const float4* q04 = reinterpret_cast<const float4*>(qw0);
        const float4* q14 = reinterpret_cast<const float4*>(qw1);
        const float4* wv4 = reinterpret_cast<const float4*>(wvs);
        float4 c0 = kr[0], c1 = kr[1];
#pragma unroll 4
        for (int h4 = 0; h4 < 64; h4 += 2) {
            const int nx = (h4 + 2) & 63;        // wraps harmlessly on last iter
            const float4 n0 = kr[nx];
            const float4 n1 = kr[nx + 1];
            {
                const float4 qa = q04[h4], qb = q14[h4], w = wv4[h4];
                a0 = fmaf(w.x, fast_rcp(1.0f + fast_exp2(qa.x + c0.x)), a0);
                a1 = fmaf(w.x, fast_rcp(1.0f + fast_exp2(qb.x + c0.x)), a1);
                a0 = fmaf(w.y, fast_rcp(1.0f + fast_exp2(qa.y + c0.y)), a0);
                a1 = fmaf(w.y, fast_rcp(1.0f + fast_exp2(qb.y + c0.y)), a1);
                a0 = fmaf(w.z, fast_rcp(1.0f + fast_exp2(qa.z + c0.z)), a0);
                a1 = fmaf(w.z, fast_rcp(1.0f + fast_exp2(qb.z + c0.z)), a1);
                a0 = fmaf(w.w, fast_rcp(1.0f + fast_exp2(qa.w + c0.w)), a0);
                a1 = fmaf(w.w, fast_rcp(1.0f + fast_exp2(qb.w + c0.w)), a1);
            }
            {
                const float4 qa = q04[h4 + 1], qb = q14[h4 + 1], w = wv4[h4 + 1];
                a0 = fmaf(w.x, fast_rcp(1.0f + fast_exp2(qa.x + c1.x)), a0);
                a1 = fmaf(w.x, fast_rcp(1.0f + fast_exp2(qb.x + c1.x)), a1);
                a0 = fmaf(w.y, fast_rcp(1.0f + fast_exp2(qa.y + c1.y)), a0);
                a1 = fmaf(w.y, fast_rcp(1.0f + fast_exp2(qb.y + c1.y)), a1);
                a0 = fmaf(w.z, fast_rcp(1.0f + fast_exp2(qa.z + c1.z)), a0);
                a1 = fmaf(w.z, fast_rcp(1.0f + fast_exp2(qb.z + c1.z)), a1);
                a0 = fmaf(w.w, fast_rcp(1.0f + fast_exp2(qa.w + c1.w)), a0);
                a1 = fmaf(w.w, fast_rcp(1.0f + fast_exp2(qb.w + c1.w)), a1);
            }
            c0 = n0; c1 = n1;
        }
    }

    // ---- masked softmax over k (min of acc == max of score) ----
    const bool valid = (k < len);
    const float BIG = 3.0e38f;

    float m0 = wave_red_min(valid ? a0 : BIG);
    float m1 = wave_red_min(valid ? a1 : BIG);
    if (lane == 0) { redm[0][wid] = m0; redm[1][wid] = m1; }
    __syncthreads();
    float mr0 = redm[0][0], mr1 = redm[1][0];
#pragma unroll
    for (int i = 1; i < 8; ++i) { mr0 = fminf(mr0, redm[0][i]); mr1 = fminf(mr1, redm[1][i]); }

    const float e0 = valid ? fast_exp2((mr0 - a0) * KSCALE) : 0.f;
    const float e1 = valid ? fast_exp2((mr1 - a1) * KSCALE) : 0.f;
    pe2[k] = make_float2(e0, e1);
    float S0 = wave_red_sum(e0);
    float S1 = wave_red_sum(e1);
    if (lane == 0) { reds[0][wid] = S0; reds[1][wid] = S1; }
    __syncthreads();
    float s0 = 0.f, s1 = 0.f;
#pragma unroll
    for (int i = 0; i < 8; ++i) { s0 += reds[0][i]; s1 += reds[1][i]; }
    const float rs0 = 1.0f / s0, rs1 = 1.0f / s1;

    // ---- PV: 2-way split-k, dead 64-k chunks skipped ----
    const int d = t & 255;
    const int half = t >> 8;
    float c0 = 0.f, c1 = 0.f;
    const float* vb = values + (size_t)b * (TK_ * D_) + (size_t)(half * 256) * D_ + d;
    const float2* pb = &pe2[half * 256];
#pragma unroll
    for (int c = 0; c < 4; ++c) {
        if (half * 256 + c * 64 < len) {
#pragma unroll 8
            for (int i = 0; i < 64; ++i) {
                const int kk = c * 64 + i;
                const float v = vb[(size_t)kk * D_];
                const float2 p = pb[kk];
                c0 = fmaf(p.x, v, c0);
                c1 = fmaf(p.y, v, c1);
            }
        }
    }
    if (half == 1) { acch[0][d] = c0; acch[1][d] = c1; }
    __syncthreads();
    if (half == 0) {
        float* ob = out + ((size_t)b * TQ_ + q0) * D_ + d;
        ob[0]  = (c0 + acch[0][d]) * rs0;
        ob[D_] = (c1 + acch[1][d]) * rs1;
    }
}

extern "C" void kernel_launch(void* const* d_in, const int* in_sizes, int n_in,
                              void* d_out, int out_size, void* d_ws, size_t ws_size,
                              hipStream_t stream) {
    const float* queries    = (const float*)d_in[0];
    const float* keys       = (const float*)d_in[1];
    const float* values     = (const float*)d_in[2];
    const int*   valid_lens = (const int*)  d_in[3];
    const float* Wq         = (const float*)d_in[4];
    const float* Wk         = (const float*)d_in[5];
    const float* wv         = (const float*)d_in[6];
    float* out = (float*)d_out;

    float* qp = (float*)d_ws;                        // B*Tq*H  = 262144 f32
    float* kp = qp + (size_t)B_ * TQ_ * H_;          // B*Tk*H  = 1048576 f32

    proj_kernel<<<320, 512, 0, stream>>>(queries, keys, Wq, Wk, valid_lens, qp, kp);
    attn_kernel<<<dim3(B_, TQ_ / 2), 512, 0, stream>>>(qp, kp, values, valid_lens, wv, out);
}